// Round 3
// baseline (54.107 us; speedup 1.0000x reference)
//
#include <hip/hip_runtime.h>

// Encoder is dead code; LSTM input is constant zero => batch dim is uniform.
// Real work: one 512-wide LSTM, 16 serial steps, broadcast 16x4 scalars to
// (16,1024,4). Cross-block h exchange via self-synchronizing packed 64-bit
// words (tag<<32 | float bits), parity double-buffered, exact-tag polling.
// This revision collapses each step into the wave: lane = (k,gate,quarter),
// per-wave publish, one barrier per step, no gate LDS round trip.

#define NBLK   16
#define NTHR   512
#define HID    512
#define TSTEPS 16

__device__ __forceinline__ float sigm(float x) { return 1.0f / (1.0f + expf(-x)); }

__global__ __launch_bounds__(NTHR, 2) void lstm_seq_kernel(
    const float* __restrict__ Whh,
    const float* __restrict__ bih,
    const float* __restrict__ bhh,
    const float* __restrict__ Wo,
    const float* __restrict__ bo,
    float* __restrict__ out,
    unsigned long long* __restrict__ slots)   // [2][512] packed (tag, h)
{
  const int tid = threadIdx.x;
  const int b   = blockIdx.x;        // block b owns k in [b*32, b*32+32)
  const int w   = tid >> 6;          // wave 0..7, owns k_block = 4w..4w+3
  const int l   = tid & 63;
  const int kl  = l >> 4;            // k_local 0..3
  const int g   = (l >> 2) & 3;      // gate (torch order i,f,g,o)
  const int q   = l & 3;             // column quarter (128 cols)
  const int k   = b * 32 + w * 4 + kl;   // global hidden index this lane owns
  const int row = g * HID + k;           // gate-row of Whh

  // h double-buffer: 4 quarters x 33 float4 (132-float stride) per parity.
  // Reads: 4 distinct addrs/instr at banks {4j,4j+4,4j+8,4j+12} -> conflict-
  // free broadcast to 16 lanes each.
  __shared__ float4 buf4[2][4 * 33];
  __shared__ float  c1s[HID];
  __shared__ float  hstash[HID];     // h_{b+1} for this block's output row
  __shared__ float  vals[4];
  float* buff = reinterpret_cast<float*>(buf4);   // [2][528] float view

  // Weights in registers: one 128-col slice of one gate-row (128 VGPRs).
  float4 wreg[32];
  {
    const float4* Wr = reinterpret_cast<const float4*>(
        Whh + (size_t)row * HID + (size_t)q * 128);
#pragma unroll
    for (int j = 0; j < 32; ++j) wreg[j] = Wr[j];
  }
  const float bias = bih[row] + bhh[row];   // kx==0 => input contrib = bih+bhh

  // --- step 1: h0 == 0, gates are pure bias -> everyone computes h1 locally
  {
    const float gi = bih[tid]           + bhh[tid];
    const float gf = bih[HID + tid]     + bhh[HID + tid];
    const float gg = bih[2 * HID + tid] + bhh[2 * HID + tid];
    const float go = bih[3 * HID + tid] + bhh[3 * HID + tid];
    const float c1 = sigm(gf) * 0.0f + sigm(gi) * tanhf(gg);
    const float h1 = sigm(go) * tanhf(c1);
    buff[528 + ((tid >> 7) * 132) + (tid & 127)] = h1;   // parity(step1)=1
    c1s[tid] = c1;
    if (b == 0) hstash[tid] = h1;
  }
  __syncthreads();
  float c_state = c1s[k];            // every lane of the k-group holds c for k

  // --- steps 2..16: body(s) consumes h_{s-1}, produces + publishes h_s ---
  for (int s = 2; s <= TSTEPS; ++s) {
    const int p = s & 1;
    const float4* hq = &buf4[p ^ 1][q * 33];

    float4 a = make_float4(0.f, 0.f, 0.f, 0.f);
#pragma unroll
    for (int j = 0; j < 32; ++j) {
      const float4 h4 = hq[j];
      a.x = fmaf(wreg[j].x, h4.x, a.x);
      a.y = fmaf(wreg[j].y, h4.y, a.y);
      a.z = fmaf(wreg[j].z, h4.z, a.z);
      a.w = fmaf(wreg[j].w, h4.w, a.w);
    }
    float d = (a.x + a.y) + (a.z + a.w);
    d += __shfl_xor(d, 1);           // reduce over the 4 column quarters
    d += __shfl_xor(d, 2);
    d += bias;                       // same bias in all 4 q-lanes of a row

    const int base = l & 48;         // k-group start lane
    const float gi = __shfl(d, base);
    const float gf = __shfl(d, base + 4);
    const float gg = __shfl(d, base + 8);
    const float go = __shfl(d, base + 12);

    c_state = sigm(gf) * c_state + sigm(gi) * tanhf(gg);
    const float hv = sigm(go) * tanhf(c_state);

    if ((l & 15) == 0) {             // one publisher per k
      const unsigned long long pk =
          ((unsigned long long)(unsigned)s << 32) |
          (unsigned long long)__float_as_uint(hv);
      __hip_atomic_store(&slots[(size_t)p * HID + k], pk,
                         __ATOMIC_RELAXED, __HIP_MEMORY_SCOPE_AGENT);
    }
    asm volatile("" ::: "memory");   // keep publish above the poll loop

    // stage h_s (everyone for s<16; only block 15 needs h_16)
    if (s < TSTEPS || b == NBLK - 1) {
      const size_t idx = (size_t)p * HID + tid;
      unsigned long long v;
      do {
        v = __hip_atomic_load(&slots[idx], __ATOMIC_RELAXED,
                              __HIP_MEMORY_SCOPE_AGENT);
      } while ((unsigned)(v >> 32) != (unsigned)s);
      const float h = __uint_as_float((unsigned)v);
      buff[p * 528 + ((tid >> 7) * 132) + (tid & 127)] = h;
      if (s == b + 1) hstash[tid] = h;
      __syncthreads();               // block-uniform branch
    }
  }

  // --- output row t = b: 4 dot products of length 512, then broadcast ---
  if (tid < 256) {
    const int wo = tid >> 6;  // output dim 0..3 (one wave each)
    const int ll = tid & 63;
    float s = 0.0f;
#pragma unroll
    for (int j = 0; j < 8; ++j) {
      const int kk = ll + 64 * j;
      s = fmaf(Wo[wo * HID + kk], hstash[kk], s);
    }
#pragma unroll
    for (int m = 32; m > 0; m >>= 1) s += __shfl_xor(s, m);
    if (ll == 0) vals[wo] = s + bo[wo];
  }
  __syncthreads();

  const float4 v = make_float4(vals[0], vals[1], vals[2], vals[3]);
  float4* out4 = reinterpret_cast<float4*>(out) + (size_t)b * 1024;
  out4[tid]       = v;   // row t=b : 1024 batch rows x 4 floats
  out4[tid + 512] = v;
}

extern "C" void kernel_launch(void* const* d_in, const int* in_sizes, int n_in,
                              void* d_out, int out_size, void* d_ws, size_t ws_size,
                              hipStream_t stream) {
  // setup_inputs() order:
  // 0 images, 1 W1, 2 b1, 3 W2, 4 b2, 5 W3, 6 b3, 7 We, 8 be,
  // 9 Wih, 10 Whh, 11 bih, 12 bhh, 13 Wg, 14 bg, 15 Wk, 16 bk,
  // 17 Wo, 18 bo, 19 Wc, 20 bc
  const float* Whh = (const float*)d_in[10];
  const float* bih = (const float*)d_in[11];
  const float* bhh = (const float*)d_in[12];
  const float* Wo  = (const float*)d_in[17];
  const float* bo  = (const float*)d_in[18];
  float* out = (float*)d_out;

  // 8 KB of exchange slots. No reset needed: exact-tag matching makes stale
  // values (previous replay: same tags, same deterministic values) and poison
  // (0xAAAAAAAA tag, never in 2..16) both harmless.
  unsigned long long* slots;
  if (d_ws != nullptr && ws_size >= 2 * HID * sizeof(unsigned long long)) {
    slots = (unsigned long long*)d_ws;
  } else {
    // Fallback: tail of out row 15. Only block 15 reads slots at s=16 and it
    // overwrites this region strictly after those reads; all producer stores
    // to slots were observed by pollers before block 15's final writes.
    slots = (unsigned long long*)(out + (size_t)out_size) - 2 * HID;
  }

  lstm_seq_kernel<<<dim3(NBLK), dim3(NTHR), 0, stream>>>(
      Whh, bih, bhh, Wo, bo, out, slots);
}

// Round 4
// 35.996 us; speedup vs baseline: 1.5032x; 1.5032x over previous
//
#include <hip/hip_runtime.h>

// Encoder is dead code; LSTM input is constant zero => batch dim is uniform.
// Real work: one 512-wide LSTM, 16 serial steps, broadcast 16x4 scalars to
// (16,1024,4). Cross-block h exchange via self-synchronizing packed 64-bit
// words (tag<<32 | float bits), parity double-buffered, exact-tag polling.
// This revision: 32 blocks (halves per-CU weight-load, doubles load CUs) and
// a wave-chunk layout: wave w owns h-cols [64w,64w+64), lane l owns one
// gate-row. Poll feeds FMA with no barrier (wave-private LDS chunk); one
// barrier per step; reducer lane holds all 4 gates of its k (no shuffles).

#define NBLK   32
#define NTHR   512
#define HID    512
#define TSTEPS 16
#define KPB    16      // k's (hidden units) owned per block = HID/NBLK
#define OUTB   16      // blocks that write output rows

__device__ __forceinline__ float sigm(float x) { return 1.0f / (1.0f + expf(-x)); }

__global__ __launch_bounds__(NTHR, 2) void lstm_seq_kernel(
    const float* __restrict__ Whh,
    const float* __restrict__ bih,
    const float* __restrict__ bhh,
    const float* __restrict__ Wo,
    const float* __restrict__ bo,
    float* __restrict__ out,
    unsigned long long* __restrict__ slots)   // [2][512] packed (tag, h)
{
  const int tid = threadIdx.x;
  const int b   = blockIdx.x;
  const int w   = tid >> 6;          // wave id = h column chunk (64 cols)
  const int l   = tid & 63;          // lane = block-local gate-row
  const int g   = l >> 4;            // gate (torch order i,f,g,o)
  const int kk  = l & 15;            // k within block
  const int grow = g * HID + b * KPB + kk;   // global gate-row of Whh

  __shared__ __align__(16) float chbuf[8][64];  // per-wave h chunk (exclusive)
  __shared__ float gpT[8][64];       // partial sums, [wave][row] (<=2-way bk)
  __shared__ float hstash[HID];      // h_{b+1} for this block's output row
  __shared__ float vals[4];

  // ---- step 1: h0 == 0 -> gates are pure bias. Wave-0 lanes<16 own the
  // block's k's end-to-end: compute c1,h1 and publish tag 1 immediately.
  float c_state = 0.0f;
  float bs_i = 0.f, bs_f = 0.f, bs_g = 0.f, bs_o = 0.f;
  if (tid < KPB) {
    const int k = b * KPB + tid;
    bs_i = bih[k]           + bhh[k];
    bs_f = bih[HID + k]     + bhh[HID + k];
    bs_g = bih[2*HID + k]   + bhh[2*HID + k];
    bs_o = bih[3*HID + k]   + bhh[3*HID + k];
    c_state = sigm(bs_f) * 0.0f + sigm(bs_i) * tanhf(bs_g);
    const float h1 = sigm(bs_o) * tanhf(c_state);
    const unsigned long long pk =
        (1ull << 32) | (unsigned long long)__float_as_uint(h1);
    __hip_atomic_store(&slots[HID + b * KPB + tid], pk,
                       __ATOMIC_RELAXED, __HIP_MEMORY_SCOPE_AGENT);
  }

  // ---- weights: one 64-col slice of one gate-row per lane (64 VGPRs) ----
  float4 wreg[16];
  {
    const float4* Wr = reinterpret_cast<const float4*>(
        Whh + (size_t)grow * HID + w * 64);
#pragma unroll
    for (int j = 0; j < 16; ++j) wreg[j] = Wr[j];
  }

  // ---- steps 2..16: poll h_{s-1} -> FMA -> reduce -> publish h_s ----
  for (int s = 2; s <= TSTEPS; ++s) {
    const int p = s & 1;

    // poll this lane's single h element (tag s-1, parity p^1)
    float h;
    {
      const size_t idx = (size_t)(p ^ 1) * HID + (size_t)w * 64 + l;
      unsigned long long v;
      do {
        v = __hip_atomic_load(&slots[idx], __ATOMIC_RELAXED,
                              __HIP_MEMORY_SCOPE_AGENT);
      } while ((unsigned)(v >> 32) != (unsigned)(s - 1));
      h = __uint_as_float((unsigned)v);
    }
    if (b < OUTB - 1 && s == b + 2) hstash[w * 64 + l] = h;  // h_{b+1}
    chbuf[w][l] = h;   // wave-private region: same-wave DS order, no barrier

    // partial dot: row grow, cols [64w,64w+64)
    float4 a = make_float4(0.f, 0.f, 0.f, 0.f);
    {
      const float4* hq = reinterpret_cast<const float4*>(&chbuf[w][0]);
#pragma unroll
      for (int j = 0; j < 16; ++j) {
        const float4 h4 = hq[j];   // broadcast read: conflict-free
        a.x = fmaf(wreg[j].x, h4.x, a.x);
        a.y = fmaf(wreg[j].y, h4.y, a.y);
        a.z = fmaf(wreg[j].z, h4.z, a.z);
        a.w = fmaf(wreg[j].w, h4.w, a.w);
      }
    }
    gpT[w][l] = (a.x + a.y) + (a.z + a.w);
    __syncthreads();   // the ONLY barrier per step

    // reducer lane k: sum 8 chunk-partials per gate, pointwise, publish.
    // (Cross-step WAR on gpT is safe: a wave writes step-s+1 partials only
    // after observing its own block's tag-s publish, which follows these
    // reads by data dependence.)
    if (tid < KPB) {
      float p0 = 0.f, p1 = 0.f, p2 = 0.f, p3 = 0.f;
#pragma unroll
      for (int j = 0; j < 8; ++j) {
        p0 += gpT[j][tid];
        p1 += gpT[j][16 + tid];
        p2 += gpT[j][32 + tid];
        p3 += gpT[j][48 + tid];
      }
      const float gi = p0 + bs_i, gf = p1 + bs_f;
      const float gg = p2 + bs_g, go = p3 + bs_o;
      c_state = sigm(gf) * c_state + sigm(gi) * tanhf(gg);
      const float hv = sigm(go) * tanhf(c_state);
      const unsigned long long pk =
          ((unsigned long long)(unsigned)s << 32) |
          (unsigned long long)__float_as_uint(hv);
      __hip_atomic_store(&slots[(size_t)p * HID + b * KPB + tid], pk,
                         __ATOMIC_RELAXED, __HIP_MEMORY_SCOPE_AGENT);
    }
  }

  if (b >= OUTB) return;   // blocks 16..31 only feed the recurrence

  // block 15 needs h_16 (tag 16, parity 0) — never polled in-loop
  if (b == OUTB - 1) {
    const size_t idx = (size_t)w * 64 + l;
    unsigned long long v;
    do {
      v = __hip_atomic_load(&slots[idx], __ATOMIC_RELAXED,
                            __HIP_MEMORY_SCOPE_AGENT);
    } while ((unsigned)(v >> 32) != (unsigned)TSTEPS);
    hstash[w * 64 + l] = __uint_as_float((unsigned)v);
  }
  __syncthreads();

  // ---- output row t = b: 4 dot products of length 512, then broadcast ----
  if (tid < 256) {
    const int wo = tid >> 6;  // output dim 0..3 (one wave each)
    const int ll = tid & 63;
    float sacc = 0.0f;
#pragma unroll
    for (int j = 0; j < 8; ++j) {
      const int k2 = ll + 64 * j;
      sacc = fmaf(Wo[wo * HID + k2], hstash[k2], sacc);
    }
#pragma unroll
    for (int m = 32; m > 0; m >>= 1) sacc += __shfl_xor(sacc, m);
    if (ll == 0) vals[wo] = sacc + bo[wo];
  }
  __syncthreads();

  const float4 vv = make_float4(vals[0], vals[1], vals[2], vals[3]);
  float4* out4 = reinterpret_cast<float4*>(out) + (size_t)b * 1024;
  out4[tid]       = vv;   // row t=b : 1024 batch rows x 4 floats
  out4[tid + 512] = vv;
}

extern "C" void kernel_launch(void* const* d_in, const int* in_sizes, int n_in,
                              void* d_out, int out_size, void* d_ws, size_t ws_size,
                              hipStream_t stream) {
  // setup_inputs() order:
  // 0 images, 1 W1, 2 b1, 3 W2, 4 b2, 5 W3, 6 b3, 7 We, 8 be,
  // 9 Wih, 10 Whh, 11 bih, 12 bhh, 13 Wg, 14 bg, 15 Wk, 16 bk,
  // 17 Wo, 18 bo, 19 Wc, 20 bc
  const float* Whh = (const float*)d_in[10];
  const float* bih = (const float*)d_in[11];
  const float* bhh = (const float*)d_in[12];
  const float* Wo  = (const float*)d_in[17];
  const float* bo  = (const float*)d_in[18];
  float* out = (float*)d_out;

  // 8 KB of exchange slots. No reset needed: exact-tag matching makes stale
  // values (previous replay: same tags, same deterministic values; poll for
  // tag t only ever races stale tags t+14/t+15 or 0xAAAAAAAA poison) harmless.
  unsigned long long* slots;
  if (d_ws != nullptr && ws_size >= 2 * HID * sizeof(unsigned long long)) {
    slots = (unsigned long long*)d_ws;
  } else {
    // Fallback: tail of out row 15. Only block 15 reads slots after the loop
    // and it overwrites this region strictly after those reads.
    slots = (unsigned long long*)(out + (size_t)out_size) - 2 * HID;
  }

  lstm_seq_kernel<<<dim3(NBLK), dim3(NTHR), 0, stream>>>(
      Whh, bih, bhh, Wo, bo, out, slots);
}